// Round 1
// baseline (1774.604 us; speedup 1.0000x reference)
//
#include <hip/hip_runtime.h>
#include <hip/hip_bf16.h>

#define E   384   // embedding dim
#define H   512   // hidden dim
#define KS  384   // K * SUB
#define AH  64    // alpha hidden
#define NK  6     // num slots
#define SUB 64    // sub dim
#define BQ  64    // num queries
#define TD  16    // docs per block

typedef float v4f __attribute__((ext_vector_type(4)));

// ---------------------------------------------------------------------------
// Kernel 1: query prep. One block per query. Produces qwT[m][b] (KS x BQ),
// where qwT[m][b] = alpha[b][m/64] * s_hat[b][m]  (pre-scaled, transposed so
// score-phase reads are coalesced across the 64 query lanes).
// ---------------------------------------------------------------------------
__global__ __launch_bounds__(256) void qprep_kernel(
    const float* __restrict__ q,
    const float* __restrict__ W1, const float* __restrict__ b1,
    const float* __restrict__ W2, const float* __restrict__ b2,
    const float* __restrict__ Wa1, const float* __restrict__ ba1,
    const float* __restrict__ Wa2, const float* __restrict__ ba2,
    float* __restrict__ qwT)
{
    __shared__ float x[E];
    __shared__ float h[H];
    __shared__ float s[KS];
    __shared__ float ah[AH];
    __shared__ float alpha[NK];
    __shared__ float ninv[NK];

    const int b = blockIdx.x;
    const int t = threadIdx.x;
    const float* qb = q + b * E;

    for (int i = t; i < E; i += 256) x[i] = qb[i];
    __syncthreads();

    // h = relu(x @ W1 + b1)
    for (int j = t; j < H; j += 256) {
        float acc = b1[j];
        for (int i = 0; i < E; ++i) acc = fmaf(x[i], W1[i * H + j], acc);
        h[j] = fmaxf(acc, 0.0f);
    }
    // ah = relu(x @ Wa1 + ba1)
    if (t < AH) {
        float acc = ba1[t];
        for (int i = 0; i < E; ++i) acc = fmaf(x[i], Wa1[i * AH + t], acc);
        ah[t] = fmaxf(acc, 0.0f);
    }
    __syncthreads();

    // s = h @ W2 + b2
    for (int m = t; m < KS; m += 256) {
        float acc = b2[m];
        for (int j = 0; j < H; ++j) acc = fmaf(h[j], W2[j * KS + m], acc);
        s[m] = acc;
    }
    __syncthreads();

    // per-slot inverse norms + alpha logits
    if (t < NK) {
        float acc = 0.0f;
        for (int d = 0; d < SUB; ++d) { float v = s[t * SUB + d]; acc = fmaf(v, v, acc); }
        ninv[t] = 1.0f / sqrtf(acc + 1e-12f);
        float lg = ba2[t];
        for (int i = 0; i < AH; ++i) lg = fmaf(ah[i], Wa2[i * NK + t], lg);
        alpha[t] = lg;  // logits for now
    }
    __syncthreads();
    if (t == 0) {
        float mx = alpha[0];
        for (int k = 1; k < NK; ++k) mx = fmaxf(mx, alpha[k]);
        float e[NK], ssum = 0.0f;
        for (int k = 0; k < NK; ++k) { e[k] = expf(alpha[k] - mx); ssum += e[k]; }
        float inv = 1.0f / ssum;
        for (int k = 0; k < NK; ++k) alpha[k] = e[k] * inv;
    }
    __syncthreads();

    for (int m = t; m < KS; m += 256) {
        qwT[m * BQ + b] = alpha[m >> 6] * ninv[m >> 6] * s[m];
    }
}

// ---------------------------------------------------------------------------
// Kernel 2: fused doc encode + score. TD=16 docs per 256-thread block.
//   stage x(16x384) -> h = relu(x@W1+b1) (16x512, LDS)
//   -> s = h@W2+b2 (reuses x buffer) -> per-slot normalize in place
//   -> out[b, p] = qwT[:, b] . s_hat[p]  for all 64 b.
// LDS: xs 16x388x4=24.8K + hs 16x512x4=32.8K + ninv -> ~58 KB => 2 blocks/CU.
// ---------------------------------------------------------------------------
__global__ __launch_bounds__(256, 2) void docscore_kernel(
    const float* __restrict__ doc,
    const float* __restrict__ W1, const float* __restrict__ b1,
    const float* __restrict__ W2, const float* __restrict__ b2,
    const float* __restrict__ qwT,
    float* __restrict__ out,
    int Pd)
{
    __shared__ float xs[TD][E + 4];   // doc tile, later holds s; +4 pad breaks stride-384 bank aliasing
    __shared__ float hs[TD][H];
    __shared__ float ninv[TD][NK];

    const int t  = threadIdx.x;
    const int p0 = blockIdx.x * TD;
    const int ndocs = min(TD, Pd - p0);

    // ---- stage doc tile (vectorized, coalesced; pad-aware scatter) ----
    {
        const v4f* src = reinterpret_cast<const v4f*>(doc + (size_t)p0 * E);
        const int limit = ndocs * (E / 4);
        for (int idx = t; idx < TD * (E / 4); idx += 256) {
            v4f v = (idx < limit) ? src[idx] : (v4f)0.0f;
            int d = idx / (E / 4);
            int c = idx % (E / 4);
            reinterpret_cast<v4f*>(&xs[d][0])[c] = v;
        }
    }
    __syncthreads();

    const int colg = t & 63;
    const int dg   = t >> 6;
    const int d0   = dg * 4;

    // ---- GEMM1: hs = relu(xs @ W1 + b1); thread = 4 docs x 8 cols ----
    {
        const int j0 = colg * 8;
        v4f acc0[4], acc1[4];
        #pragma unroll
        for (int i = 0; i < 4; ++i) { acc0[i] = 0.0f; acc1[i] = 0.0f; }
        const float* wp = W1 + j0;
        for (int k = 0; k < E; k += 4) {
            v4f a[4];
            #pragma unroll
            for (int i = 0; i < 4; ++i) a[i] = *reinterpret_cast<const v4f*>(&xs[d0 + i][k]);
            #pragma unroll
            for (int kk = 0; kk < 4; ++kk) {
                v4f w0 = *reinterpret_cast<const v4f*>(wp);
                v4f w1 = *reinterpret_cast<const v4f*>(wp + 4);
                #pragma unroll
                for (int i = 0; i < 4; ++i) {
                    float av = a[i][kk];
                    acc0[i] += av * w0;
                    acc1[i] += av * w1;
                }
                wp += H;
            }
        }
        v4f bb0 = *reinterpret_cast<const v4f*>(b1 + j0);
        v4f bb1 = *reinterpret_cast<const v4f*>(b1 + j0 + 4);
        #pragma unroll
        for (int i = 0; i < 4; ++i) {
            v4f h0 = acc0[i] + bb0;
            v4f h1 = acc1[i] + bb1;
            #pragma unroll
            for (int c = 0; c < 4; ++c) { h0[c] = fmaxf(h0[c], 0.0f); h1[c] = fmaxf(h1[c], 0.0f); }
            *reinterpret_cast<v4f*>(&hs[d0 + i][j0])     = h0;
            *reinterpret_cast<v4f*>(&hs[d0 + i][j0 + 4]) = h1;
        }
    }
    __syncthreads();

    // ---- GEMM2: s = hs @ W2 + b2 -> xs; thread = 4 docs x 6 cols ----
    {
        const int m0 = colg * 6;
        float acc[4][6];
        #pragma unroll
        for (int i = 0; i < 4; ++i)
            #pragma unroll
            for (int c = 0; c < 6; ++c) acc[i][c] = 0.0f;
        const float* wp = W2 + m0;
        for (int j = 0; j < H; j += 4) {
            v4f a[4];
            #pragma unroll
            for (int i = 0; i < 4; ++i) a[i] = *reinterpret_cast<const v4f*>(&hs[d0 + i][j]);
            #pragma unroll
            for (int jj = 0; jj < 4; ++jj) {
                float2 w01 = *reinterpret_cast<const float2*>(wp);
                float2 w23 = *reinterpret_cast<const float2*>(wp + 2);
                float2 w45 = *reinterpret_cast<const float2*>(wp + 4);
                float wv[6] = {w01.x, w01.y, w23.x, w23.y, w45.x, w45.y};
                #pragma unroll
                for (int i = 0; i < 4; ++i) {
                    float av = a[i][jj];
                    #pragma unroll
                    for (int c = 0; c < 6; ++c) acc[i][c] = fmaf(av, wv[c], acc[i][c]);
                }
                wp += KS;
            }
        }
        #pragma unroll
        for (int i = 0; i < 4; ++i)
            #pragma unroll
            for (int c = 0; c < 6; ++c)
                xs[d0 + i][m0 + c] = acc[i][c] + b2[m0 + c];
    }
    __syncthreads();

    // ---- per (doc, slot) inverse norms ----
    if (t < TD * NK) {
        int d = t / NK, k = t % NK;
        float acc = 0.0f;
        for (int c = 0; c < SUB; ++c) { float v = xs[d][k * SUB + c]; acc = fmaf(v, v, acc); }
        ninv[d][k] = 1.0f / sqrtf(acc + 1e-12f);
    }
    __syncthreads();

    // ---- scale s in place by per-slot inverse norm ----
    for (int idx = t; idx < TD * E; idx += 256) {
        int d = idx / E, m = idx % E;
        xs[d][m] *= ninv[d][m >> 6];
    }
    __syncthreads();

    // ---- score: thread = 1 query b x 4 docs ----
    {
        const int b = t & 63;
        float acc[4] = {0.0f, 0.0f, 0.0f, 0.0f};
        for (int j = 0; j < KS; j += 4) {
            v4f a[4];
            #pragma unroll
            for (int i = 0; i < 4; ++i) a[i] = *reinterpret_cast<const v4f*>(&xs[d0 + i][j]);
            float qv[4];
            #pragma unroll
            for (int jj = 0; jj < 4; ++jj) qv[jj] = qwT[(j + jj) * BQ + b];
            #pragma unroll
            for (int i = 0; i < 4; ++i)
                #pragma unroll
                for (int jj = 0; jj < 4; ++jj)
                    acc[i] = fmaf(a[i][jj], qv[jj], acc[i]);
        }
        const int p = p0 + d0;
        if (d0 + 3 < ndocs) {
            float4 o; o.x = acc[0]; o.y = acc[1]; o.z = acc[2]; o.w = acc[3];
            *reinterpret_cast<float4*>(out + (size_t)b * Pd + p) = o;
        } else {
            for (int i = 0; i < 4; ++i)
                if (d0 + i < ndocs) out[(size_t)b * Pd + p + i] = acc[i];
        }
    }
}

extern "C" void kernel_launch(void* const* d_in, const int* in_sizes, int n_in,
                              void* d_out, int out_size, void* d_ws, size_t ws_size,
                              hipStream_t stream) {
    const float* qe  = (const float*)d_in[0];
    const float* de  = (const float*)d_in[1];
    const float* W1  = (const float*)d_in[2];
    const float* b1  = (const float*)d_in[3];
    const float* W2  = (const float*)d_in[4];
    const float* b2  = (const float*)d_in[5];
    const float* Wa1 = (const float*)d_in[6];
    const float* ba1 = (const float*)d_in[7];
    const float* Wa2 = (const float*)d_in[8];
    const float* ba2 = (const float*)d_in[9];
    float* out = (float*)d_out;
    float* qwT = (float*)d_ws;           // KS x BQ floats = 98304 B

    const int Pd = in_sizes[1] / E;      // 100000

    qprep_kernel<<<BQ, 256, 0, stream>>>(qe, W1, b1, W2, b2, Wa1, ba1, Wa2, ba2, qwT);

    const int nblk = (Pd + TD - 1) / TD;
    docscore_kernel<<<nblk, 256, 0, stream>>>(de, W1, b1, W2, b2, qwT, out, Pd);
}

// Round 2
// 803.939 us; speedup vs baseline: 2.2074x; 2.2074x over previous
//
#include <hip/hip_runtime.h>
#include <hip/hip_bf16.h>

#define E   384
#define H   512
#define KS  384
#define AH  64
#define NK  6
#define SUB 64
#define BQ  64

typedef short bf16x8 __attribute__((ext_vector_type(8)));
typedef float f32x4  __attribute__((ext_vector_type(4)));

__device__ __forceinline__ unsigned short f2bf(float f) {
    union { float f; unsigned int u; } c; c.f = f;
    unsigned int u = c.u;
    unsigned int r = (u + 0x7fffu + ((u >> 16) & 1u)) >> 16;   // RNE
    return (unsigned short)r;
}
__device__ __forceinline__ float bf2f(unsigned short b) {
    union { unsigned int u; float f; } c; c.u = ((unsigned int)b) << 16;
    return c.f;
}

// ---------------------------------------------------------------------------
// Kernel 1: query prep (fp32). qw[b*KS + m] = alpha[b][m/64] * s_hat[b][m].
// ---------------------------------------------------------------------------
__global__ __launch_bounds__(256) void qprep_kernel(
    const float* __restrict__ q,
    const float* __restrict__ W1, const float* __restrict__ b1,
    const float* __restrict__ W2, const float* __restrict__ b2,
    const float* __restrict__ Wa1, const float* __restrict__ ba1,
    const float* __restrict__ Wa2, const float* __restrict__ ba2,
    float* __restrict__ qw)
{
    __shared__ float x[E];
    __shared__ float h[H];
    __shared__ float s[KS];
    __shared__ float ah[AH];
    __shared__ float alpha[NK];
    __shared__ float ninv[NK];

    const int b = blockIdx.x;
    const int t = threadIdx.x;
    const float* qb = q + b * E;

    for (int i = t; i < E; i += 256) x[i] = qb[i];
    __syncthreads();

    for (int j = t; j < H; j += 256) {
        float acc = b1[j];
        for (int i = 0; i < E; ++i) acc = fmaf(x[i], W1[i * H + j], acc);
        h[j] = fmaxf(acc, 0.0f);
    }
    if (t < AH) {
        float acc = ba1[t];
        for (int i = 0; i < E; ++i) acc = fmaf(x[i], Wa1[i * AH + t], acc);
        ah[t] = fmaxf(acc, 0.0f);
    }
    __syncthreads();

    for (int m = t; m < KS; m += 256) {
        float acc = b2[m];
        for (int j = 0; j < H; ++j) acc = fmaf(h[j], W2[j * KS + m], acc);
        s[m] = acc;
    }
    __syncthreads();

    if (t < NK) {
        float acc = 0.0f;
        for (int d = 0; d < SUB; ++d) { float v = s[t * SUB + d]; acc = fmaf(v, v, acc); }
        ninv[t] = 1.0f / sqrtf(acc + 1e-12f);
        float lg = ba2[t];
        for (int i = 0; i < AH; ++i) lg = fmaf(ah[i], Wa2[i * NK + t], lg);
        alpha[t] = lg;
    }
    __syncthreads();
    if (t == 0) {
        float mx = alpha[0];
        for (int k = 1; k < NK; ++k) mx = fmaxf(mx, alpha[k]);
        float e[NK], ssum = 0.0f;
        for (int k = 0; k < NK; ++k) { e[k] = expf(alpha[k] - mx); ssum += e[k]; }
        float inv = 1.0f / ssum;
        for (int k = 0; k < NK; ++k) alpha[k] = e[k] * inv;
    }
    __syncthreads();

    for (int m = t; m < KS; m += 256)
        qw[b * KS + m] = alpha[m >> 6] * ninv[m >> 6] * s[m];
}

// ---------------------------------------------------------------------------
// Kernel 2: pack W1, W2, qw into MFMA B-fragment layout (bf16).
// Fragment for mfma_f32_16x16x32_bf16 B-operand: lane l holds
// B[k = kt*32 + (l>>4)*8 + j][n = nt*16 + (l&15)], j=0..7 contiguous.
// W1p frag id = nt*12 + kt (nt<32, kt<12); W2p = nt*16+kt (nt<24, kt<16);
// qwp = nt*12+kt (nt<4, kt<12).
// ---------------------------------------------------------------------------
__global__ void pack_kernel(const float* __restrict__ W1,
                            const float* __restrict__ W2,
                            const float* __restrict__ qw,
                            unsigned short* __restrict__ W1p,
                            unsigned short* __restrict__ W2p,
                            unsigned short* __restrict__ qwp)
{
    int f = blockIdx.x;
    const int l = threadIdx.x;
    const int lq = l >> 4, ln = l & 15;
    if (f < 384) {
        int nt = f / 12, kt = f % 12;
        int k0 = kt * 32 + lq * 8, n = nt * 16 + ln;
        unsigned short* dst = W1p + (size_t)f * 512 + l * 8;
        #pragma unroll
        for (int j = 0; j < 8; ++j) dst[j] = f2bf(W1[(size_t)(k0 + j) * H + n]);
    } else if (f < 768) {
        f -= 384;
        int nt = f / 16, kt = f % 16;
        int k0 = kt * 32 + lq * 8, n = nt * 16 + ln;
        unsigned short* dst = W2p + (size_t)f * 512 + l * 8;
        #pragma unroll
        for (int j = 0; j < 8; ++j) dst[j] = f2bf(W2[(size_t)(k0 + j) * KS + n]);
    } else {
        f -= 768;
        int nt = f / 12, kt = f % 12;
        int k0 = kt * 32 + lq * 8, b = nt * 16 + ln;
        unsigned short* dst = qwp + (size_t)f * 512 + l * 8;
        const float* src = qw + (size_t)b * KS + k0;
        #pragma unroll
        for (int j = 0; j < 8; ++j) dst[j] = f2bf(src[j]);
    }
}

// ---------------------------------------------------------------------------
// Kernel 3: fused doc encode + score, MFMA 16x16x32 bf16.
// Block = 256 threads = 4 waves; wave owns 16 docs (M=16).
// Per-wave private 16KB LDS slab: holds H (16x512 bf16, XOR-chunk swizzle),
// then reused for s (16x384 bf16) + ninv (16x6 fp32 at offset 6144 shorts).
// A-frags in registers; B-frags streamed from packed weights (L1/L2).
// ---------------------------------------------------------------------------
__global__ __launch_bounds__(256, 2) void docscore_mfma(
    const float* __restrict__ doc,
    const unsigned short* __restrict__ W1p, const float* __restrict__ b1,
    const unsigned short* __restrict__ W2p, const float* __restrict__ b2,
    const unsigned short* __restrict__ qwp,
    float* __restrict__ out, int Pd)
{
    __shared__ short hs[4][8192];   // 64 KB: 16 KB per wave
    const int tid  = threadIdx.x;
    const int wave = tid >> 6, l = tid & 63;
    const int lq = l >> 4, ln = l & 15;
    short* slab = hs[wave];

    const int p0 = blockIdx.x * 64 + wave * 16;
    const int pr = min(p0 + ln, Pd - 1);     // clamped A-row source
    const int rowbase = 4 * lq;

    const bf16x8* W1f = (const bf16x8*)W1p;
    const bf16x8* W2f = (const bf16x8*)W2p;
    const bf16x8* qwf = (const bf16x8*)qwp;

    // ---- doc A-frags: 12 ktiles, fp32 -> bf16 ----
    bf16x8 xf[12];
    {
        const float* src = doc + (size_t)pr * E + lq * 8;
        #pragma unroll
        for (int kt = 0; kt < 12; ++kt) {
            float4 a = *(const float4*)(src + kt * 32);
            float4 b = *(const float4*)(src + kt * 32 + 4);
            bf16x8 v;
            v[0] = (short)f2bf(a.x); v[1] = (short)f2bf(a.y);
            v[2] = (short)f2bf(a.z); v[3] = (short)f2bf(a.w);
            v[4] = (short)f2bf(b.x); v[5] = (short)f2bf(b.y);
            v[6] = (short)f2bf(b.z); v[7] = (short)f2bf(b.w);
            xf[kt] = v;
        }
    }

    // ---- GEMM1: H = relu(X@W1 + b1) -> slab (swizzled) ----
    for (int nt = 0; nt < 32; ++nt) {
        f32x4 acc0 = {0.f, 0.f, 0.f, 0.f}, acc1 = {0.f, 0.f, 0.f, 0.f};
        const bf16x8* bp = W1f + (size_t)nt * 12 * 64 + l;
        #pragma unroll
        for (int kt = 0; kt < 12; kt += 2) {
            acc0 = __builtin_amdgcn_mfma_f32_16x16x32_bf16(xf[kt],     bp[(size_t)kt * 64],       acc0, 0, 0, 0);
            acc1 = __builtin_amdgcn_mfma_f32_16x16x32_bf16(xf[kt + 1], bp[(size_t)(kt + 1) * 64], acc1, 0, 0, 0);
        }
        float bias = b1[nt * 16 + ln];
        int kcol = nt * 16 + ln;
        int chunk = kcol >> 3, klo = kcol & 7;
        #pragma unroll
        for (int r = 0; r < 4; ++r) {
            int row = rowbase + r;
            float v = fmaxf(acc0[r] + acc1[r] + bias, 0.0f);
            slab[row * 512 + ((chunk ^ (row & 7)) << 3) + klo] = (short)f2bf(v);
        }
    }
    __syncthreads();

    // ---- GEMM2: S = H@W2 + b2; s kept packed in regs, sumsq in regs ----
    bf16x8 hfr[16];
    #pragma unroll
    for (int kt = 0; kt < 16; ++kt) {
        int chunk = (kt * 4 + lq) ^ (ln & 7);
        hfr[kt] = *(const bf16x8*)&slab[ln * 512 + (chunk << 3)];
    }

    unsigned int spk[48];
    float sq[24];
    #pragma unroll
    for (int i = 0; i < 24; ++i) sq[i] = 0.0f;

    #pragma unroll
    for (int nt = 0; nt < 24; ++nt) {
        f32x4 acc0 = {0.f, 0.f, 0.f, 0.f}, acc1 = {0.f, 0.f, 0.f, 0.f};
        const bf16x8* bp = W2f + (size_t)nt * 16 * 64 + l;
        #pragma unroll
        for (int kt = 0; kt < 16; kt += 2) {
            acc0 = __builtin_amdgcn_mfma_f32_16x16x32_bf16(hfr[kt],     bp[(size_t)kt * 64],       acc0, 0, 0, 0);
            acc1 = __builtin_amdgcn_mfma_f32_16x16x32_bf16(hfr[kt + 1], bp[(size_t)(kt + 1) * 64], acc1, 0, 0, 0);
        }
        float bias = b2[nt * 16 + ln];
        int slot = nt >> 2;
        float v0 = acc0[0] + acc1[0] + bias;
        float v1 = acc0[1] + acc1[1] + bias;
        float v2 = acc0[2] + acc1[2] + bias;
        float v3 = acc0[3] + acc1[3] + bias;
        sq[slot * 4 + 0] += v0 * v0;
        sq[slot * 4 + 1] += v1 * v1;
        sq[slot * 4 + 2] += v2 * v2;
        sq[slot * 4 + 3] += v3 * v3;
        spk[nt * 2 + 0] = (unsigned int)f2bf(v0) | ((unsigned int)f2bf(v1) << 16);
        spk[nt * 2 + 1] = (unsigned int)f2bf(v2) | ((unsigned int)f2bf(v3) << 16);
    }

    // cross-lane reduce sumsq over the 16 columns (lanes within quarter)
    #pragma unroll
    for (int d = 1; d < 16; d <<= 1) {
        #pragma unroll
        for (int i = 0; i < 24; ++i) sq[i] += __shfl_xor(sq[i], d, 64);
    }

    __syncthreads();

    // ninv: rows rowbase..rowbase+3 x 6 slots, written by lanes ln<6
    float* nv = (float*)&slab[6144];
    if (ln < NK) {
        #pragma unroll
        for (int r = 0; r < 4; ++r)
            nv[(rowbase + r) * NK + ln] = rsqrtf(sq[ln * 4 + r] + 1e-12f);
    }
    // s -> slab (bf16, stride 384, swizzled), overwrite H region
    #pragma unroll
    for (int nt = 0; nt < 24; ++nt) {
        int kcol = nt * 16 + ln;
        int chunk = kcol >> 3, klo = kcol & 7;
        #pragma unroll
        for (int r = 0; r < 4; ++r) {
            int row = rowbase + r;
            unsigned short bits = (spk[nt * 2 + (r >> 1)] >> ((r & 1) * 16)) & 0xffffu;
            slab[row * 384 + ((chunk ^ (row & 7)) << 3) + klo] = (short)bits;
        }
    }
    __syncthreads();

    // ---- score: A-frags = s_hat (scaled on load), B = qwp ----
    bf16x8 sf[12];
    #pragma unroll
    for (int kt = 0; kt < 12; ++kt) {
        int k0 = kt * 32 + lq * 8;
        int chunk = (k0 >> 3) ^ (ln & 7);
        bf16x8 raw = *(const bf16x8*)&slab[ln * 384 + (chunk << 3)];
        float nin = nv[ln * NK + (k0 >> 6)];
        bf16x8 o;
        #pragma unroll
        for (int j = 0; j < 8; ++j)
            o[j] = (short)f2bf(bf2f((unsigned short)raw[j]) * nin);
        sf[kt] = o;
    }

    #pragma unroll
    for (int nt = 0; nt < 4; ++nt) {
        f32x4 acc0 = {0.f, 0.f, 0.f, 0.f}, acc1 = {0.f, 0.f, 0.f, 0.f};
        const bf16x8* bp = qwf + (size_t)nt * 12 * 64 + l;
        #pragma unroll
        for (int kt = 0; kt < 12; kt += 2) {
            acc0 = __builtin_amdgcn_mfma_f32_16x16x32_bf16(sf[kt],     bp[(size_t)kt * 64],       acc0, 0, 0, 0);
            acc1 = __builtin_amdgcn_mfma_f32_16x16x32_bf16(sf[kt + 1], bp[(size_t)(kt + 1) * 64], acc1, 0, 0, 0);
        }
        int q  = nt * 16 + ln;
        int pb = p0 + rowbase;
        float* op = out + (size_t)q * Pd + pb;
        float r0 = acc0[0] + acc1[0];
        float r1 = acc0[1] + acc1[1];
        float r2 = acc0[2] + acc1[2];
        float r3 = acc0[3] + acc1[3];
        if (pb + 3 < Pd) {
            float4 o; o.x = r0; o.y = r1; o.z = r2; o.w = r3;
            *(float4*)op = o;
        } else {
            float rr[4] = {r0, r1, r2, r3};
            for (int i = 0; i < 4; ++i)
                if (pb + i < Pd) op[i] = rr[i];
        }
    }
}

extern "C" void kernel_launch(void* const* d_in, const int* in_sizes, int n_in,
                              void* d_out, int out_size, void* d_ws, size_t ws_size,
                              hipStream_t stream) {
    const float* qe  = (const float*)d_in[0];
    const float* de  = (const float*)d_in[1];
    const float* W1  = (const float*)d_in[2];
    const float* b1  = (const float*)d_in[3];
    const float* W2  = (const float*)d_in[4];
    const float* b2  = (const float*)d_in[5];
    const float* Wa1 = (const float*)d_in[6];
    const float* ba1 = (const float*)d_in[7];
    const float* Wa2 = (const float*)d_in[8];
    const float* ba2 = (const float*)d_in[9];
    float* out = (float*)d_out;

    // ws layout (all 16B-aligned offsets)
    float*          qw  = (float*)d_ws;                                  //  98304 B
    unsigned short* W1p = (unsigned short*)((char*)d_ws + 98304);        // 393216 B
    unsigned short* W2p = (unsigned short*)((char*)d_ws + 491520);       // 393216 B
    unsigned short* qwp = (unsigned short*)((char*)d_ws + 884736);       //  49152 B

    const int Pd = in_sizes[1] / E;   // 100000

    qprep_kernel<<<BQ, 256, 0, stream>>>(qe, W1, b1, W2, b2, Wa1, ba1, Wa2, ba2, qw);
    pack_kernel<<<816, 64, 0, stream>>>(W1, W2, qw, W1p, W2p, qwp);

    const int nblk = (Pd + 63) / 64;
    docscore_mfma<<<nblk, 256, 0, stream>>>(de, W1p, b1, W2p, b2, qwp, out, Pd);
}